// Round 8
// baseline (250.197 us; speedup 1.0000x reference)
//
#include <hip/hip_runtime.h>
#include <math.h>
#include <stdint.h>

#define HH 480
#define WW 640
#define HW (HH*WW)
#define KK 512
#define DD 256
#define KP1 513
#define NSLOT 16
#define NBX 40
#define NBY 30
#define SLOTS_PER_IMG (NBX*NBY*NSLOT)   /* 19200 */
#define SVCAP 2048
#define SBK 16                           /* sinkhorn blocks */
#define NORM_F (-6.9314718055994531f)   /* -log(1024) */
#define LOGK_F (6.2383246250395077f)    /* log(512) */
#define MU0 (1.0f/1024.0f)
#define MU1 (0.5f)

// ---------------- ws layout (bytes) ----------------
#define OFF_FLAGS  0u          /* SBK ints, 128B-strided (2048 B) */
#define OFF_Z      16384u      /* 512*512*4 = 1048576 (dense, stride 512) */
#define OFF_SMOOTH 2473984u    /* 2 * HW f32 */
#define OFF_CAND   4931584u    /* 2 * 19200 u64 = 307200 */
#define OFF_KIDX   5238784u    /* 2 * 512 int */
#define OFF_DESC   5242880u    /* 2 * 512 * 256 f32 */
#define OFF_SBUF   6291456u    /* 2 * 512 f32 */
#define OFF_PC     6295552u    /* 2 * SBK * 513 f32 = 65664 */

// ---------------------------------------------------------------------------
// BAD pair offsets: numpy RandomState(42).randint(-8,9,(256,4)), compile-time.
// ---------------------------------------------------------------------------
struct OffsTab { int v[1024]; };
static constexpr OffsTab make_offsets() {
  OffsTab o{};
  unsigned st[624] = {};
  st[0] = 42u;
  for (int i = 1; i < 624; ++i)
    st[i] = 1812433253u*(st[i-1] ^ (st[i-1] >> 30)) + (unsigned)i;
  int idx = 624, got = 0;
  while (got < 1024) {
    if (idx == 624) {
      for (int i = 0; i < 624; ++i) {
        unsigned y = (st[i] & 0x80000000u) | (st[(i+1)%624] & 0x7fffffffu);
        st[i] = st[(i+397)%624] ^ (y >> 1) ^ ((y & 1u) ? 2567483615u : 0u);
      }
      idx = 0;
    }
    unsigned y = st[idx++];
    y ^= y >> 11;
    y ^= (y << 7)  & 2636928640u;
    y ^= (y << 15) & 4022730752u;
    y ^= y >> 18;
    unsigned mv = y & 31u;
    if (mv <= 16u) { o.v[got] = (int)mv - 8; ++got; }
  }
  return o;
}
__device__ __constant__ OffsTab OFFS = make_offsets();

// ---------------------------------------------------------------------------
// Fused detector + NMS (bit-exact selection path; unchanged since round 6).
// ---------------------------------------------------------------------------
__global__ __launch_bounds__(256) void detnms_kernel(const float* __restrict__ img0,
    const float* __restrict__ img1, float* __restrict__ smooth,
    unsigned long long* __restrict__ cand) {
  __shared__ float tile[26][26];
  __shared__ float ixA[24][24], iyA[24][24];
  __shared__ float sc[22][22];
  __shared__ float vs[16][26];
  __shared__ float vm[16][22];
  __shared__ int wsum[4], wbase[4];
  const int imgI = blockIdx.z;
  const float* img = imgI ? img1 : img0;
  const int bx0 = blockIdx.x*16, by0 = blockIdx.y*16;
  const int tx = threadIdx.x, ty = threadIdx.y, lt = ty*16+tx;
  for (int p = lt; p < 676; p += 256) {
    int r = p/26, c = p%26;
    int gy = by0-5+r, gx = bx0-5+c;
    tile[r][c] = (gy >= 0 && gy < HH && gx >= 0 && gx < WW) ? img[gy*WW+gx] : 0.f;
  }
  __syncthreads();
  for (int p = lt; p < 576; p += 256) {
    int r = p/24, c = p%24;
    int gy = by0-4+r, gx = bx0-4+c;
    float ix = 0.f, iy = 0.f;
    if (gy >= 0 && gy < HH && gx >= 0 && gx < WW) {
      float t00 = tile[r][c],   t01 = tile[r][c+1],   t02 = tile[r][c+2];
      float t10 = tile[r+1][c],                        t12 = tile[r+1][c+2];
      float t20 = tile[r+2][c], t21 = tile[r+2][c+1], t22 = tile[r+2][c+2];
      ix = t00*(-1.f) + t02*1.f + t10*(-2.f) + t12*2.f + t20*(-1.f) + t22*1.f;
      iy = t00*(-1.f) + t01*(-2.f) + t02*(-1.f) + t20*1.f + t21*2.f + t22*1.f;
    }
    ixA[r][c] = ix; iyA[r][c] = iy;
  }
  __syncthreads();
  const float c9 = 1.f/9.f, c25 = 1.f/25.f;
  for (int p = lt; p < 484; p += 256) {
    int r = p/22, c = p%22;
    int gy = by0-3+r, gx = bx0-3+c;
    float v = -INFINITY;
    if (gy >= 0 && gy < HH && gx >= 0 && gx < WW) {
      float sxx = 0.f, syy = 0.f, sxy = 0.f;
      for (int dr = 0; dr < 3; ++dr)
        for (int dc = 0; dc < 3; ++dc) {
          float jx = ixA[r+dr][c+dc], jy = iyA[r+dr][c+dc];
          float pxxv = jx*jx, pyyv = jy*jy, pxyv = jx*jy;
          sxx += pxxv*c9; syy += pyyv*c9; sxy += pxyv*c9;
        }
      float tdif = sxx - syy;
      v = 0.5f * ((sxx + syy) - sqrtf(tdif*tdif + 4.f*(sxy*sxy) + 1e-12f));
    }
    sc[r][c] = v;
  }
  for (int p = lt; p < 416; p += 256) {
    int i = p/26, c = p%26;
    vs[i][c] = tile[i+3][c] + tile[i+4][c] + tile[i+5][c] + tile[i+6][c] + tile[i+7][c];
  }
  __syncthreads();
  for (int p = lt; p < 352; p += 256) {
    int i = p/22, c = p%22;
    float m = sc[i][c];
    m = fmaxf(m, sc[i+1][c]); m = fmaxf(m, sc[i+2][c]); m = fmaxf(m, sc[i+3][c]);
    m = fmaxf(m, sc[i+4][c]); m = fmaxf(m, sc[i+5][c]); m = fmaxf(m, sc[i+6][c]);
    vm[i][c] = m;
  }
  float sm = (vs[ty][tx+3] + vs[ty][tx+4] + vs[ty][tx+5] + vs[ty][tx+6] + vs[ty][tx+7]) * c25;
  smooth[imgI*HW + (by0+ty)*WW + (bx0+tx)] = sm;
  __syncthreads();
  float cv = sc[ty+3][tx+3];
  float m = vm[ty][tx];
  m = fmaxf(m, vm[ty][tx+1]); m = fmaxf(m, vm[ty][tx+2]); m = fmaxf(m, vm[ty][tx+3]);
  m = fmaxf(m, vm[ty][tx+4]); m = fmaxf(m, vm[ty][tx+5]); m = fmaxf(m, vm[ty][tx+6]);
  bool pred = (cv >= m && cv > 0.f);
  unsigned long long mask = __ballot(pred);
  int lane = lt & 63, wid = lt >> 6;
  if (lane == 0) wsum[wid] = __popcll(mask);
  __syncthreads();
  if (lt == 0) {
    int s0 = wsum[0], s1 = wsum[1], s2 = wsum[2], s3 = wsum[3];
    wbase[0] = 0; wbase[1] = s0; wbase[2] = s0+s1; wbase[3] = s0+s1+s2;
    wsum[0] = s0+s1+s2+s3;
  }
  __syncthreads();
  const int total = wsum[0];
  const size_t slotBase = (size_t)imgI*SLOTS_PER_IMG + (size_t)(blockIdx.y*NBX + blockIdx.x)*NSLOT;
  if (pred) {
    int pos = wbase[wid] + __popcll(mask & ((1ull << lane) - 1ull));
    if (pos < NSLOT) {
      int idx = (by0+ty)*WW + (bx0+tx);
      unsigned int ub = __float_as_uint(cv) | 0x80000000u;
      cand[slotBase + pos] = ((unsigned long long)ub << 32) | (unsigned int)(~idx);
    }
  }
  if (lt >= total && lt < NSLOT) cand[slotBase + lt] = 0ull;
}

// ---------------------------------------------------------------------------
// Fused top-512 select (unchanged since round 7).
// ---------------------------------------------------------------------------
__global__ __launch_bounds__(1024) void select2_kernel(const unsigned long long* __restrict__ cand,
    float* __restrict__ kptsOut, int* __restrict__ kidx) {
  __shared__ unsigned long long sk[SVCAP];
  __shared__ int hist[1024];
  __shared__ int sB1, sB2, sNeed, sCount;
  const int imgI = blockIdx.x, t = threadIdx.x;
  const unsigned long long* cd = cand + (size_t)imgI*SLOTS_PER_IMG;
  unsigned long long kreg[19];
  #pragma unroll
  for (int r = 0; r < 19; ++r) {
    int i = t + r*1024;
    kreg[r] = (i < SLOTS_PER_IMG) ? cd[i] : 0ull;
  }
  hist[t] = 0;
  if (t == 0) { sB1 = -1; sB2 = 0; sCount = 0; }
  __syncthreads();
  #pragma unroll
  for (int r = 0; r < 19; ++r)
    if (kreg[r]) atomicAdd(&hist[(int)(kreg[r] >> 54)], 1);
  __syncthreads();
  for (int d = 1; d < 1024; d <<= 1) {
    int vv = hist[t] + ((t + d < 1024) ? hist[t + d] : 0);
    __syncthreads();
    hist[t] = vv;
    __syncthreads();
  }
  if (hist[t] >= KK) atomicMax(&sB1, t);
  __syncthreads();
  const int b1 = sB1;
  if (t == 0 && b1 >= 0) sNeed = KK - ((b1 < 1023) ? hist[b1 + 1] : 0);
  __syncthreads();
  int b2 = 0;
  if (b1 >= 0) {
    hist[t] = 0;
    __syncthreads();
    #pragma unroll
    for (int r = 0; r < 19; ++r) {
      unsigned long long k = kreg[r];
      if (k && (int)(k >> 54) == b1) atomicAdd(&hist[(int)(k >> 44) & 1023], 1);
    }
    __syncthreads();
    for (int d = 1; d < 1024; d <<= 1) {
      int vv = hist[t] + ((t + d < 1024) ? hist[t + d] : 0);
      __syncthreads();
      hist[t] = vv;
      __syncthreads();
    }
    if (hist[t] >= sNeed) atomicMax(&sB2, t);
    __syncthreads();
    b2 = sB2;
  }
  #pragma unroll
  for (int r = 0; r < 19; ++r) {
    unsigned long long k = kreg[r];
    if (k) {
      int bin1 = (int)(k >> 54);
      if (bin1 > b1 || (bin1 == b1 && ((int)(k >> 44) & 1023) >= b2)) {
        int pos = atomicAdd(&sCount, 1);
        if (pos < SVCAP) sk[pos] = k;
      }
    }
  }
  __syncthreads();
  const int n = (sCount < SVCAP) ? sCount : SVCAP;
  for (int k = n + t; k < KK; k += 1024) {
    kptsOut[imgI*2*KK + 2*k]     = -1.f;
    kptsOut[imgI*2*KK + 2*k + 1] = -1.f;
    kidx[imgI*KK + k] = -1;
  }
  for (int i = t; i < n; i += 1024) {
    unsigned long long key = sk[i];
    int r = 0;
    for (int m = 0; m < n; ++m) r += (sk[m] > key) ? 1 : 0;
    if (r < KK) {
      int id = (int)(~(unsigned int)(key & 0xFFFFFFFFull));
      kptsOut[imgI*2*KK + 2*r]     = (float)(id / WW);
      kptsOut[imgI*2*KK + 2*r + 1] = (float)(id % WW);
      kidx[imgI*KK + r] = id;
    }
  }
}

// ---------------------------------------------------------------------------
// Per-keypoint BAD descriptor + L2 norm + squared-norm (unchanged).
// ---------------------------------------------------------------------------
__global__ __launch_bounds__(256) void desc_kernel(const float* __restrict__ smooth,
    const int* __restrict__ kidx, float* __restrict__ desc, float* __restrict__ sbuf) {
  __shared__ float wsum[4];
  const int k = blockIdx.x, imgI = blockIdx.y;
  const int j = threadIdx.x;
  const int id = kidx[imgI*KK + k];
  float val = 0.f;
  if (id >= 0) {
    int y = id / WW, x = id % WW;
    int o0 = OFFS.v[4*j], o1 = OFFS.v[4*j+1], o2 = OFFS.v[4*j+2], o3 = OFFS.v[4*j+3];
    const float* sm = smooth + imgI*HW;
    int ya = min(max(y+o0, 0), HH-1), xa = min(max(x+o1, 0), WW-1);
    int yb = min(max(y+o2, 0), HH-1), xb = min(max(x+o3, 0), WW-1);
    val = sm[ya*WW + xa] - sm[yb*WW + xb];
  }
  float ss = val*val;
  for (int off = 32; off; off >>= 1) ss += __shfl_down(ss, off);
  if ((j & 63) == 0) wsum[j >> 6] = ss;
  __syncthreads();
  if (j == 0) wsum[0] = wsum[0] + wsum[1] + wsum[2] + wsum[3];
  __syncthreads();
  float tot = wsum[0];
  float inv = 1.f / (sqrtf(tot) + 1e-12f);
  desc[((size_t)imgI*KK + k)*DD + j] = val * inv;
  if (j == 0) sbuf[imgI*KK + k] = tot * inv * inv;
}

// ---------------------------------------------------------------------------
// Z (dense 512x512), 32x32 tile, 2x2 per thread. Also zeroes the SBK barrier
// flags (stream-ordered before the cooperative sinkhorn; replaces memset).
// ---------------------------------------------------------------------------
__global__ __launch_bounds__(256) void zbuild_kernel(const float* __restrict__ desc,
    const float* __restrict__ sbuf, float* __restrict__ Z, int* __restrict__ flags) {
  __shared__ float sA[32][260], sB[32][260];
  const int ty = threadIdx.y, tx = threadIdx.x;
  const int i0 = blockIdx.y*32, j0 = blockIdx.x*32;
  const int lt = ty*16 + tx;
  if (blockIdx.x == 0 && blockIdx.y == 0 && lt < SBK) flags[lt << 5] = 0;
  for (int p = lt; p < 32*DD; p += 256) {
    int r = p >> 8, c = p & 255;
    sA[r][c] = desc[((size_t)(i0 + r))*DD + c];
    sB[r][c] = desc[((size_t)(KK + j0 + r))*DD + c];
  }
  __syncthreads();
  const float4* pa0 = (const float4*)&sA[ty][0];
  const float4* pa1 = (const float4*)&sA[ty+16][0];
  const float4* pb0 = (const float4*)&sB[tx][0];
  const float4* pb1 = (const float4*)&sB[tx+16][0];
  float a00 = 0.f, a01 = 0.f, a10 = 0.f, a11 = 0.f;
  for (int c4 = 0; c4 < DD/4; ++c4) {
    float4 a0 = pa0[c4], a1 = pa1[c4], b0 = pb0[c4], b1 = pb1[c4];
    a00 += a0.x*b0.x; a00 += a0.y*b0.y; a00 += a0.z*b0.z; a00 += a0.w*b0.w;
    a01 += a0.x*b1.x; a01 += a0.y*b1.y; a01 += a0.z*b1.z; a01 += a0.w*b1.w;
    a10 += a1.x*b0.x; a10 += a1.y*b0.y; a10 += a1.z*b0.z; a10 += a1.w*b0.w;
    a11 += a1.x*b1.x; a11 += a1.y*b1.y; a11 += a1.z*b1.z; a11 += a1.w*b1.w;
  }
  const float s0 = sbuf[i0 + ty], s0b = sbuf[i0 + ty + 16];
  const float s1 = sbuf[KK + j0 + tx], s1b = sbuf[KK + j0 + tx + 16];
  Z[(size_t)(i0+ty)   *KK + j0+tx]    = -sqrtf(fmaxf(s0  + s1  - 2.f*a00, 1e-12f));
  Z[(size_t)(i0+ty)   *KK + j0+tx+16] = -sqrtf(fmaxf(s0  + s1b - 2.f*a01, 1e-12f));
  Z[(size_t)(i0+ty+16)*KK + j0+tx]    = -sqrtf(fmaxf(s0b + s1  - 2.f*a10, 1e-12f));
  Z[(size_t)(i0+ty+16)*KK + j0+tx+16] = -sqrtf(fmaxf(s0b + s1b - 2.f*a11, 1e-12f));
}

// ---------------------------------------------------------------------------
// Cooperative Sinkhorn v3: 16 blocks, 2 rows/wave. Barrier flags padded to one
// 128B line per block (kills the line ping-pong of v1/v2). Relaxed spin with
// bounded ACQUIRE fallback; __threadfence() after the barrier for visibility.
// ---------------------------------------------------------------------------
__global__ __launch_bounds__(1024) void sinkhorn_kernel(const float* __restrict__ Z,
    float* __restrict__ Pcol, int* flags, float* __restrict__ probs) {
  __shared__ float v[KP1];
  __shared__ float pcolw[16][516];
  const int t = threadIdx.x, b = blockIdx.x;
  const int widx = t >> 6, lane = t & 63;
  const int gw = b*16 + widx;          // wave id 0..255; rows 2*gw, 2*gw+1
  const int j0 = lane*8;
  const bool hasDust = (gw == 255);
  for (int j = t; j < KP1; j += 1024) v[j] = 0.f;
  __syncthreads();
  float uv0 = 0.f, uv1 = 0.f, uDust = 0.f;
  for (int it = 0; it < 20; ++it) {
    if (it > 0) {
      const float* pcAll = Pcol + ((it-1)&1)*(SBK*KP1);
      for (int j = t; j < KP1; j += 1024) {
        float s = 0.f;
        #pragma unroll
        for (int w = 0; w < SBK; ++w) s += pcAll[w*KP1 + j];
        float lognu = (j < KK) ? NORM_F : (LOGK_F + NORM_F);
        v[j] = lognu + v[j] - logf(s);
      }
      __syncthreads();
    }
    // ---- row pass: 2 rows per wave (+ dust row on wave 255) ----
    float4 va = *(const float4*)&v[j0];
    float4 vb = *(const float4*)&v[j0+4];
    float vv[8] = {va.x,va.y,va.z,va.w,vb.x,vb.y,vb.z,vb.w};
    const float v512 = v[512];
    float pacc[8]; float pacc8 = 0.f;
    #pragma unroll
    for (int q = 0; q < 8; ++q) pacc[q] = 0.f;
    #pragma unroll
    for (int rr = 0; rr < 2; ++rr) {
      const int r = 2*gw + rr;
      const float* zr = Z + (size_t)r*KK;
      float4 z0 = *(const float4*)&zr[j0];
      float4 z1 = *(const float4*)&zr[j0+4];
      float zv[8] = {z0.x,z0.y,z0.z,z0.w,z1.x,z1.y,z1.z,z1.w};
      float tv[8]; float S = 0.f;
      #pragma unroll
      for (int q = 0; q < 8; ++q) { tv[q] = expf(zv[q] + vv[q]); S += tv[q]; }
      float t8 = 0.f;
      if (lane == 0) { t8 = expf(1.0f + v512); S += t8; }
      #pragma unroll
      for (int off = 32; off; off >>= 1) S += __shfl_xor(S, off);
      float eu = MU0 / S;
      float u = logf(eu);
      if (rr == 0) uv0 = u; else uv1 = u;
      #pragma unroll
      for (int q = 0; q < 8; ++q) pacc[q] += tv[q] * eu;
      pacc8 += t8 * eu;
    }
    if (hasDust) {
      float tv2[8]; float S2 = 0.f;
      #pragma unroll
      for (int q = 0; q < 8; ++q) { tv2[q] = expf(1.0f + vv[q]); S2 += tv2[q]; }
      float t82 = 0.f;
      if (lane == 0) { t82 = expf(1.0f + v512); S2 += t82; }
      #pragma unroll
      for (int off = 32; off; off >>= 1) S2 += __shfl_xor(S2, off);
      float eu2 = MU1 / S2;
      uDust = logf(eu2);
      #pragma unroll
      for (int q = 0; q < 8; ++q) pacc[q] += tv2[q] * eu2;
      pacc8 += t82 * eu2;
    }
    *(float4*)&pcolw[widx][j0]   = make_float4(pacc[0], pacc[1], pacc[2], pacc[3]);
    *(float4*)&pcolw[widx][j0+4] = make_float4(pacc[4], pacc[5], pacc[6], pacc[7]);
    if (lane == 0) pcolw[widx][512] = pacc8;
    __syncthreads();
    float* pc = Pcol + (it&1)*(SBK*KP1) + b*KP1;
    for (int j = t; j < KP1; j += 1024) {
      float s = 0.f;
      #pragma unroll
      for (int w = 0; w < 16; ++w) s += pcolw[w][j];
      pc[j] = s;
    }
    // ---- grid barrier: padded flags (one 128B line per block) ----
    __syncthreads();
    const int gen = it + 1;
    if (t == 0)
      __hip_atomic_store(&flags[b << 5], gen, __ATOMIC_RELEASE, __HIP_MEMORY_SCOPE_AGENT);
    if (t < SBK) {
      int spins = 0;
      while (__hip_atomic_load(&flags[t << 5], __ATOMIC_RELAXED, __HIP_MEMORY_SCOPE_AGENT) < gen) {
        __builtin_amdgcn_s_sleep(1);
        if (++spins == 4096) {   // safety net: coherent polls, guarantees progress
          while (__hip_atomic_load(&flags[t << 5], __ATOMIC_ACQUIRE, __HIP_MEMORY_SCOPE_AGENT) < gen)
            __builtin_amdgcn_s_sleep(8);
          break;
        }
      }
    }
    __syncthreads();
    __threadfence();   // acquire side: invalidate caches so slice reads are fresh
  }
  // ---- final v-update + probs = exp(Z + u + v - norm) ----
  {
    const float* pcAll = Pcol + (19&1)*(SBK*KP1);
    for (int j = t; j < KP1; j += 1024) {
      float s = 0.f;
      #pragma unroll
      for (int w = 0; w < SBK; ++w) s += pcAll[w*KP1 + j];
      float lognu = (j < KK) ? NORM_F : (LOGK_F + NORM_F);
      v[j] = lognu + v[j] - logf(s);
    }
    __syncthreads();
  }
  float4 va = *(const float4*)&v[j0];
  float4 vb = *(const float4*)&v[j0+4];
  float vv[8] = {va.x,va.y,va.z,va.w,vb.x,vb.y,vb.z,vb.w};
  const float v512 = v[512];
  #pragma unroll
  for (int rr = 0; rr < 2; ++rr) {
    const int r = 2*gw + rr;
    const float ur = rr ? uv1 : uv0;
    const float* zr = Z + (size_t)r*KK;
    float4 z0 = *(const float4*)&zr[j0];
    float4 z1 = *(const float4*)&zr[j0+4];
    float zv[8] = {z0.x,z0.y,z0.z,z0.w,z1.x,z1.y,z1.z,z1.w};
    float* pr = probs + (size_t)r*KP1;
    #pragma unroll
    for (int q = 0; q < 8; ++q) pr[j0+q] = expf(zv[q] + ur + vv[q] - NORM_F);
    if (lane == 0) pr[512] = expf(1.0f + ur + v512 - NORM_F);
  }
  if (hasDust) {
    float* pd = probs + (size_t)512*KP1;
    #pragma unroll
    for (int q = 0; q < 8; ++q) pd[j0+q] = expf(1.0f + uDust + vv[q] - NORM_F);
    if (lane == 0) pd[512] = expf(1.0f + uDust + v512 - NORM_F);
  }
}

extern "C" void kernel_launch(void* const* d_in, const int* in_sizes, int n_in,
                              void* d_out, int out_size, void* d_ws, size_t ws_size,
                              hipStream_t stream) {
  const float* img1 = (const float*)d_in[0];
  const float* img2 = (const float*)d_in[1];
  float* out = (float*)d_out;
  char* ws = (char*)d_ws;

  int*   flags  = (int*)  (ws + OFF_FLAGS);
  float* smooth = (float*)(ws + OFF_SMOOTH);
  unsigned long long* cand = (unsigned long long*)(ws + OFF_CAND);
  int*   kidx   = (int*)  (ws + OFF_KIDX);
  float* desc   = (float*)(ws + OFF_DESC);
  float* sbuf   = (float*)(ws + OFF_SBUF);
  float* Z      = (float*)(ws + OFF_Z);
  float* pcol   = (float*)(ws + OFF_PC);
  float* probsOut = out + 2*KK*2;

  detnms_kernel<<<dim3(NBX, NBY, 2), dim3(16, 16), 0, stream>>>(img1, img2, smooth, cand);
  select2_kernel<<<2, 1024, 0, stream>>>(cand, out, kidx);
  desc_kernel<<<dim3(KK, 2), 256, 0, stream>>>(smooth, kidx, desc, sbuf);
  zbuild_kernel<<<dim3(16, 16), dim3(16, 16), 0, stream>>>(desc, sbuf, Z, flags);

  void* args[] = { (void*)&Z, (void*)&pcol, (void*)&flags, (void*)&probsOut };
  hipLaunchCooperativeKernel((const void*)sinkhorn_kernel, dim3(SBK), dim3(1024),
                             args, 0, stream);
}

// Round 9
// 138.503 us; speedup vs baseline: 1.8064x; 1.8064x over previous
//
#include <hip/hip_runtime.h>
#include <math.h>
#include <stdint.h>

#define HH 480
#define WW 640
#define HW (HH*WW)
#define KK 512
#define DD 256
#define KP1 513
#define NSLOT 16
#define NBX 40
#define NBY 30
#define SLOTS_PER_IMG (NBX*NBY*NSLOT)   /* 19200 */
#define SVCAP 2048
#define SB 32                            /* sinkhorn blocks */
#define MU0 (1.0f/1024.0f)
#define MU1 (0.5f)
#define EDUST 2.71828182845904523536f    /* exp(1.0) dustbin */

// ---------------- ws layout (bytes) ----------------
#define OFF_E      16384u      /* E = exp(Z), dense 512x512 f32 */
#define OFF_SMOOTH 2473984u    /* 2 * HW f32 */
#define OFF_CAND   4931584u    /* 2 * 19200 u64 = 307200 */
#define OFF_KIDX   5238784u    /* 2 * 512 int */
#define OFF_DESC   5242880u    /* 2 * 512 * 256 f32 */
#define OFF_SBUF   6291456u    /* 2 * 512 f32 */
#define OFF_PC     6295552u    /* 2 * SB * 513 f32 = 131328 */
#define OFF_EU     6426880u    /* 513 f32 */

// ---------------------------------------------------------------------------
// BAD pair offsets: numpy RandomState(42).randint(-8,9,(256,4)), compile-time.
// ---------------------------------------------------------------------------
struct OffsTab { int v[1024]; };
static constexpr OffsTab make_offsets() {
  OffsTab o{};
  unsigned st[624] = {};
  st[0] = 42u;
  for (int i = 1; i < 624; ++i)
    st[i] = 1812433253u*(st[i-1] ^ (st[i-1] >> 30)) + (unsigned)i;
  int idx = 624, got = 0;
  while (got < 1024) {
    if (idx == 624) {
      for (int i = 0; i < 624; ++i) {
        unsigned y = (st[i] & 0x80000000u) | (st[(i+1)%624] & 0x7fffffffu);
        st[i] = st[(i+397)%624] ^ (y >> 1) ^ ((y & 1u) ? 2567483615u : 0u);
      }
      idx = 0;
    }
    unsigned y = st[idx++];
    y ^= y >> 11;
    y ^= (y << 7)  & 2636928640u;
    y ^= (y << 15) & 4022730752u;
    y ^= y >> 18;
    unsigned mv = y & 31u;
    if (mv <= 16u) { o.v[got] = (int)mv - 8; ++got; }
  }
  return o;
}
__device__ __constant__ OffsTab OFFS = make_offsets();

// ---------------------------------------------------------------------------
// Fused detector + NMS (bit-exact selection path; unchanged since round 6).
// ---------------------------------------------------------------------------
__global__ __launch_bounds__(256) void detnms_kernel(const float* __restrict__ img0,
    const float* __restrict__ img1, float* __restrict__ smooth,
    unsigned long long* __restrict__ cand) {
  __shared__ float tile[26][26];
  __shared__ float ixA[24][24], iyA[24][24];
  __shared__ float sc[22][22];
  __shared__ float vs[16][26];
  __shared__ float vm[16][22];
  __shared__ int wsum[4], wbase[4];
  const int imgI = blockIdx.z;
  const float* img = imgI ? img1 : img0;
  const int bx0 = blockIdx.x*16, by0 = blockIdx.y*16;
  const int tx = threadIdx.x, ty = threadIdx.y, lt = ty*16+tx;
  for (int p = lt; p < 676; p += 256) {
    int r = p/26, c = p%26;
    int gy = by0-5+r, gx = bx0-5+c;
    tile[r][c] = (gy >= 0 && gy < HH && gx >= 0 && gx < WW) ? img[gy*WW+gx] : 0.f;
  }
  __syncthreads();
  for (int p = lt; p < 576; p += 256) {
    int r = p/24, c = p%24;
    int gy = by0-4+r, gx = bx0-4+c;
    float ix = 0.f, iy = 0.f;
    if (gy >= 0 && gy < HH && gx >= 0 && gx < WW) {
      float t00 = tile[r][c],   t01 = tile[r][c+1],   t02 = tile[r][c+2];
      float t10 = tile[r+1][c],                        t12 = tile[r+1][c+2];
      float t20 = tile[r+2][c], t21 = tile[r+2][c+1], t22 = tile[r+2][c+2];
      ix = t00*(-1.f) + t02*1.f + t10*(-2.f) + t12*2.f + t20*(-1.f) + t22*1.f;
      iy = t00*(-1.f) + t01*(-2.f) + t02*(-1.f) + t20*1.f + t21*2.f + t22*1.f;
    }
    ixA[r][c] = ix; iyA[r][c] = iy;
  }
  __syncthreads();
  const float c9 = 1.f/9.f, c25 = 1.f/25.f;
  for (int p = lt; p < 484; p += 256) {
    int r = p/22, c = p%22;
    int gy = by0-3+r, gx = bx0-3+c;
    float v = -INFINITY;
    if (gy >= 0 && gy < HH && gx >= 0 && gx < WW) {
      float sxx = 0.f, syy = 0.f, sxy = 0.f;
      for (int dr = 0; dr < 3; ++dr)
        for (int dc = 0; dc < 3; ++dc) {
          float jx = ixA[r+dr][c+dc], jy = iyA[r+dr][c+dc];
          float pxxv = jx*jx, pyyv = jy*jy, pxyv = jx*jy;
          sxx += pxxv*c9; syy += pyyv*c9; sxy += pxyv*c9;
        }
      float tdif = sxx - syy;
      v = 0.5f * ((sxx + syy) - sqrtf(tdif*tdif + 4.f*(sxy*sxy) + 1e-12f));
    }
    sc[r][c] = v;
  }
  for (int p = lt; p < 416; p += 256) {
    int i = p/26, c = p%26;
    vs[i][c] = tile[i+3][c] + tile[i+4][c] + tile[i+5][c] + tile[i+6][c] + tile[i+7][c];
  }
  __syncthreads();
  for (int p = lt; p < 352; p += 256) {
    int i = p/22, c = p%22;
    float m = sc[i][c];
    m = fmaxf(m, sc[i+1][c]); m = fmaxf(m, sc[i+2][c]); m = fmaxf(m, sc[i+3][c]);
    m = fmaxf(m, sc[i+4][c]); m = fmaxf(m, sc[i+5][c]); m = fmaxf(m, sc[i+6][c]);
    vm[i][c] = m;
  }
  float sm = (vs[ty][tx+3] + vs[ty][tx+4] + vs[ty][tx+5] + vs[ty][tx+6] + vs[ty][tx+7]) * c25;
  smooth[imgI*HW + (by0+ty)*WW + (bx0+tx)] = sm;
  __syncthreads();
  float cv = sc[ty+3][tx+3];
  float m = vm[ty][tx];
  m = fmaxf(m, vm[ty][tx+1]); m = fmaxf(m, vm[ty][tx+2]); m = fmaxf(m, vm[ty][tx+3]);
  m = fmaxf(m, vm[ty][tx+4]); m = fmaxf(m, vm[ty][tx+5]); m = fmaxf(m, vm[ty][tx+6]);
  bool pred = (cv >= m && cv > 0.f);
  unsigned long long mask = __ballot(pred);
  int lane = lt & 63, wid = lt >> 6;
  if (lane == 0) wsum[wid] = __popcll(mask);
  __syncthreads();
  if (lt == 0) {
    int s0 = wsum[0], s1 = wsum[1], s2 = wsum[2], s3 = wsum[3];
    wbase[0] = 0; wbase[1] = s0; wbase[2] = s0+s1; wbase[3] = s0+s1+s2;
    wsum[0] = s0+s1+s2+s3;
  }
  __syncthreads();
  const int total = wsum[0];
  const size_t slotBase = (size_t)imgI*SLOTS_PER_IMG + (size_t)(blockIdx.y*NBX + blockIdx.x)*NSLOT;
  if (pred) {
    int pos = wbase[wid] + __popcll(mask & ((1ull << lane) - 1ull));
    if (pos < NSLOT) {
      int idx = (by0+ty)*WW + (bx0+tx);
      unsigned int ub = __float_as_uint(cv) | 0x80000000u;
      cand[slotBase + pos] = ((unsigned long long)ub << 32) | (unsigned int)(~idx);
    }
  }
  if (lt >= total && lt < NSLOT) cand[slotBase + lt] = 0ull;
}

// ---------------------------------------------------------------------------
// Fused top-512 select (unchanged since round 7).
// ---------------------------------------------------------------------------
__global__ __launch_bounds__(1024) void select2_kernel(const unsigned long long* __restrict__ cand,
    float* __restrict__ kptsOut, int* __restrict__ kidx) {
  __shared__ unsigned long long sk[SVCAP];
  __shared__ int hist[1024];
  __shared__ int sB1, sB2, sNeed, sCount;
  const int imgI = blockIdx.x, t = threadIdx.x;
  const unsigned long long* cd = cand + (size_t)imgI*SLOTS_PER_IMG;
  unsigned long long kreg[19];
  #pragma unroll
  for (int r = 0; r < 19; ++r) {
    int i = t + r*1024;
    kreg[r] = (i < SLOTS_PER_IMG) ? cd[i] : 0ull;
  }
  hist[t] = 0;
  if (t == 0) { sB1 = -1; sB2 = 0; sCount = 0; }
  __syncthreads();
  #pragma unroll
  for (int r = 0; r < 19; ++r)
    if (kreg[r]) atomicAdd(&hist[(int)(kreg[r] >> 54)], 1);
  __syncthreads();
  for (int d = 1; d < 1024; d <<= 1) {
    int vv = hist[t] + ((t + d < 1024) ? hist[t + d] : 0);
    __syncthreads();
    hist[t] = vv;
    __syncthreads();
  }
  if (hist[t] >= KK) atomicMax(&sB1, t);
  __syncthreads();
  const int b1 = sB1;
  if (t == 0 && b1 >= 0) sNeed = KK - ((b1 < 1023) ? hist[b1 + 1] : 0);
  __syncthreads();
  int b2 = 0;
  if (b1 >= 0) {
    hist[t] = 0;
    __syncthreads();
    #pragma unroll
    for (int r = 0; r < 19; ++r) {
      unsigned long long k = kreg[r];
      if (k && (int)(k >> 54) == b1) atomicAdd(&hist[(int)(k >> 44) & 1023], 1);
    }
    __syncthreads();
    for (int d = 1; d < 1024; d <<= 1) {
      int vv = hist[t] + ((t + d < 1024) ? hist[t + d] : 0);
      __syncthreads();
      hist[t] = vv;
      __syncthreads();
    }
    if (hist[t] >= sNeed) atomicMax(&sB2, t);
    __syncthreads();
    b2 = sB2;
  }
  #pragma unroll
  for (int r = 0; r < 19; ++r) {
    unsigned long long k = kreg[r];
    if (k) {
      int bin1 = (int)(k >> 54);
      if (bin1 > b1 || (bin1 == b1 && ((int)(k >> 44) & 1023) >= b2)) {
        int pos = atomicAdd(&sCount, 1);
        if (pos < SVCAP) sk[pos] = k;
      }
    }
  }
  __syncthreads();
  const int n = (sCount < SVCAP) ? sCount : SVCAP;
  for (int k = n + t; k < KK; k += 1024) {
    kptsOut[imgI*2*KK + 2*k]     = -1.f;
    kptsOut[imgI*2*KK + 2*k + 1] = -1.f;
    kidx[imgI*KK + k] = -1;
  }
  for (int i = t; i < n; i += 1024) {
    unsigned long long key = sk[i];
    int r = 0;
    for (int m = 0; m < n; ++m) r += (sk[m] > key) ? 1 : 0;
    if (r < KK) {
      int id = (int)(~(unsigned int)(key & 0xFFFFFFFFull));
      kptsOut[imgI*2*KK + 2*r]     = (float)(id / WW);
      kptsOut[imgI*2*KK + 2*r + 1] = (float)(id % WW);
      kidx[imgI*KK + r] = id;
    }
  }
}

// ---------------------------------------------------------------------------
// Per-keypoint BAD descriptor + L2 norm + squared-norm (unchanged).
// ---------------------------------------------------------------------------
__global__ __launch_bounds__(256) void desc_kernel(const float* __restrict__ smooth,
    const int* __restrict__ kidx, float* __restrict__ desc, float* __restrict__ sbuf) {
  __shared__ float wsum[4];
  const int k = blockIdx.x, imgI = blockIdx.y;
  const int j = threadIdx.x;
  const int id = kidx[imgI*KK + k];
  float val = 0.f;
  if (id >= 0) {
    int y = id / WW, x = id % WW;
    int o0 = OFFS.v[4*j], o1 = OFFS.v[4*j+1], o2 = OFFS.v[4*j+2], o3 = OFFS.v[4*j+3];
    const float* sm = smooth + imgI*HW;
    int ya = min(max(y+o0, 0), HH-1), xa = min(max(x+o1, 0), WW-1);
    int yb = min(max(y+o2, 0), HH-1), xb = min(max(x+o3, 0), WW-1);
    val = sm[ya*WW + xa] - sm[yb*WW + xb];
  }
  float ss = val*val;
  for (int off = 32; off; off >>= 1) ss += __shfl_down(ss, off);
  if ((j & 63) == 0) wsum[j >> 6] = ss;
  __syncthreads();
  if (j == 0) wsum[0] = wsum[0] + wsum[1] + wsum[2] + wsum[3];
  __syncthreads();
  float tot = wsum[0];
  float inv = 1.f / (sqrtf(tot) + 1e-12f);
  desc[((size_t)imgI*KK + k)*DD + j] = val * inv;
  if (j == 0) sbuf[imgI*KK + k] = tot * inv * inv;
}

// ---------------------------------------------------------------------------
// E = exp(-sqrt(clip(s1+s2-2*d1.d2, 1e-12)))  (dense 512x512; dustbins are
// the constant EDUST, never stored). 32x32 tile, 2x2 outputs per thread.
// ---------------------------------------------------------------------------
__global__ __launch_bounds__(256) void zbuild_kernel(const float* __restrict__ desc,
    const float* __restrict__ sbuf, float* __restrict__ E) {
  __shared__ float sA[32][260], sB[32][260];
  const int ty = threadIdx.y, tx = threadIdx.x;
  const int i0 = blockIdx.y*32, j0 = blockIdx.x*32;
  const int lt = ty*16 + tx;
  for (int p = lt; p < 32*DD; p += 256) {
    int r = p >> 8, c = p & 255;
    sA[r][c] = desc[((size_t)(i0 + r))*DD + c];
    sB[r][c] = desc[((size_t)(KK + j0 + r))*DD + c];
  }
  __syncthreads();
  const float4* pa0 = (const float4*)&sA[ty][0];
  const float4* pa1 = (const float4*)&sA[ty+16][0];
  const float4* pb0 = (const float4*)&sB[tx][0];
  const float4* pb1 = (const float4*)&sB[tx+16][0];
  float a00 = 0.f, a01 = 0.f, a10 = 0.f, a11 = 0.f;
  for (int c4 = 0; c4 < DD/4; ++c4) {
    float4 a0 = pa0[c4], a1 = pa1[c4], b0 = pb0[c4], b1 = pb1[c4];
    a00 += a0.x*b0.x; a00 += a0.y*b0.y; a00 += a0.z*b0.z; a00 += a0.w*b0.w;
    a01 += a0.x*b1.x; a01 += a0.y*b1.y; a01 += a0.z*b1.z; a01 += a0.w*b1.w;
    a10 += a1.x*b0.x; a10 += a1.y*b0.y; a10 += a1.z*b0.z; a10 += a1.w*b0.w;
    a11 += a1.x*b1.x; a11 += a1.y*b1.y; a11 += a1.z*b1.z; a11 += a1.w*b1.w;
  }
  const float s0 = sbuf[i0 + ty], s0b = sbuf[i0 + ty + 16];
  const float s1 = sbuf[KK + j0 + tx], s1b = sbuf[KK + j0 + tx + 16];
  E[(size_t)(i0+ty)   *KK + j0+tx]    = expf(-sqrtf(fmaxf(s0  + s1  - 2.f*a00, 1e-12f)));
  E[(size_t)(i0+ty)   *KK + j0+tx+16] = expf(-sqrtf(fmaxf(s0  + s1b - 2.f*a01, 1e-12f)));
  E[(size_t)(i0+ty+16)*KK + j0+tx]    = expf(-sqrtf(fmaxf(s0b + s1  - 2.f*a10, 1e-12f)));
  E[(size_t)(i0+ty+16)*KK + j0+tx+16] = expf(-sqrtf(fmaxf(s0b + s1b - 2.f*a11, 1e-12f)));
}

// ---------------------------------------------------------------------------
// Transcendental-free Sinkhorn step on E = exp(Z):
//   ev_j = nu_j / G_j   (mode 0: ev = 1),  G_j = sum_w PcolIn slices
//   S_i  = sum_j E_ij*ev_j + EDUST*ev_512 ;  eu_i = mu_i / S_i
//   slice G_j(block) = sum_{rows in block} E_ij*eu_i  (+ dust row in block 31)
//   mode 2: probs = E*eu*ev*1024.
// 32 blocks x 16 waves = 512 waves; wave owns one row (wave 511 also dustrow).
// All sums fixed-order -> deterministic; launch boundary is the grid barrier.
// ---------------------------------------------------------------------------
__global__ __launch_bounds__(1024) void sink_step_kernel(const float* __restrict__ E,
    const float* __restrict__ PcolIn, float* __restrict__ PcolOut,
    float* __restrict__ euBuf, float* __restrict__ probs, int mode) {
  __shared__ float ev[KP1];
  __shared__ float pcolw[16][520];
  const int t = threadIdx.x, b = blockIdx.x;
  const int widx = t >> 6, lane = t & 63;
  const int r = b*16 + widx;          // row 0..511
  const int j0 = lane*8;
  if (mode == 0) {
    for (int j = t; j < KP1; j += 1024) ev[j] = 1.f;
  } else {
    for (int j = t; j < KP1; j += 1024) {
      float s = 0.f;
      #pragma unroll
      for (int w = 0; w < SB; ++w) s += PcolIn[w*KP1 + j];
      float nu = (j < KK) ? MU0 : MU1;
      ev[j] = nu / s;
    }
  }
  __syncthreads();
  float4 va = *(const float4*)&ev[j0];
  float4 vb = *(const float4*)&ev[j0+4];
  float evv[8] = {va.x,va.y,va.z,va.w,vb.x,vb.y,vb.z,vb.w};
  const float ev512 = ev[512];
  const float* er = E + (size_t)r*KK;
  float4 e0 = *(const float4*)&er[j0];
  float4 e1 = *(const float4*)&er[j0+4];
  float ee[8] = {e0.x,e0.y,e0.z,e0.w,e1.x,e1.y,e1.z,e1.w};
  if (mode == 2) {
    const float euR = euBuf[r];
    float* pr = probs + (size_t)r*KP1;
    #pragma unroll
    for (int q = 0; q < 8; ++q) pr[j0+q] = ee[q] * euR * evv[q] * 1024.f;
    if (lane == 0) pr[512] = EDUST * euR * ev512 * 1024.f;
    if (r == 511) {
      const float euD = euBuf[512];
      float* pd = probs + (size_t)512*KP1;
      #pragma unroll
      for (int q = 0; q < 8; ++q) pd[j0+q] = EDUST * euD * evv[q] * 1024.f;
      if (lane == 0) pd[512] = EDUST * euD * ev512 * 1024.f;
    }
    return;
  }
  // ---- row pass (pure FMA) ----
  float S = 0.f;
  #pragma unroll
  for (int q = 0; q < 8; ++q) S += ee[q] * evv[q];
  if (lane == 0) S += EDUST * ev512;
  #pragma unroll
  for (int off = 32; off; off >>= 1) S += __shfl_xor(S, off);
  const float euR = MU0 / S;
  if (lane == 0) euBuf[r] = euR;
  float pacc[8];
  #pragma unroll
  for (int q = 0; q < 8; ++q) pacc[q] = ee[q] * euR;
  float pacc8 = EDUST * euR;
  if (r == 511) {       // dust row: S_d = EDUST * sum(ev)
    float Sd = 0.f;
    #pragma unroll
    for (int q = 0; q < 8; ++q) Sd += evv[q];
    if (lane == 0) Sd += ev512;
    #pragma unroll
    for (int off = 32; off; off >>= 1) Sd += __shfl_xor(Sd, off);
    Sd *= EDUST;
    const float euD = MU1 / Sd;
    if (lane == 0) euBuf[512] = euD;
    #pragma unroll
    for (int q = 0; q < 8; ++q) pacc[q] += EDUST * euD;
    pacc8 += EDUST * euD;
  }
  *(float4*)&pcolw[widx][j0]   = make_float4(pacc[0], pacc[1], pacc[2], pacc[3]);
  *(float4*)&pcolw[widx][j0+4] = make_float4(pacc[4], pacc[5], pacc[6], pacc[7]);
  if (lane == 0) pcolw[widx][512] = pacc8;
  __syncthreads();
  float* pc = PcolOut + b*KP1;
  for (int j = t; j < KP1; j += 1024) {
    float s = 0.f;
    #pragma unroll
    for (int w = 0; w < 16; ++w) s += pcolw[w][j];
    pc[j] = s;
  }
}

extern "C" void kernel_launch(void* const* d_in, const int* in_sizes, int n_in,
                              void* d_out, int out_size, void* d_ws, size_t ws_size,
                              hipStream_t stream) {
  const float* img1 = (const float*)d_in[0];
  const float* img2 = (const float*)d_in[1];
  float* out = (float*)d_out;
  char* ws = (char*)d_ws;

  float* smooth = (float*)(ws + OFF_SMOOTH);
  unsigned long long* cand = (unsigned long long*)(ws + OFF_CAND);
  int*   kidx   = (int*)  (ws + OFF_KIDX);
  float* desc   = (float*)(ws + OFF_DESC);
  float* sbuf   = (float*)(ws + OFF_SBUF);
  float* E      = (float*)(ws + OFF_E);
  float* pcA    = (float*)(ws + OFF_PC);
  float* pcB    = (float*)(ws + OFF_PC) + SB*KP1;
  float* euBuf  = (float*)(ws + OFF_EU);
  float* probsOut = out + 2*KK*2;

  detnms_kernel<<<dim3(NBX, NBY, 2), dim3(16, 16), 0, stream>>>(img1, img2, smooth, cand);
  select2_kernel<<<2, 1024, 0, stream>>>(cand, out, kidx);
  desc_kernel<<<dim3(KK, 2), 256, 0, stream>>>(smooth, kidx, desc, sbuf);
  zbuild_kernel<<<dim3(16, 16), dim3(16, 16), 0, stream>>>(desc, sbuf, E);

  // L0: ev=1, row pass -> pcA
  sink_step_kernel<<<SB, 1024, 0, stream>>>(E, pcB, pcA, euBuf, probsOut, 0);
  int ping = 0;  // latest slices in pcA
  for (int it = 1; it < 20; ++it) {
    float* pin  = ping ? pcB : pcA;
    float* pout = ping ? pcA : pcB;
    sink_step_kernel<<<SB, 1024, 0, stream>>>(E, pin, pout, euBuf, probsOut, 1);
    ping ^= 1;
  }
  {
    float* pin = ping ? pcB : pcA;
    sink_step_kernel<<<SB, 1024, 0, stream>>>(E, pin, pcA, euBuf, probsOut, 2);
  }
}